// Round 5
// baseline (1089.161 us; speedup 1.0000x reference)
//
#include <hip/hip_runtime.h>
#include <hip/hip_bf16.h>

typedef __hip_bfloat16 bf16;
typedef __bf16 bf16v8 __attribute__((ext_vector_type(8)));
typedef float f32x4 __attribute__((ext_vector_type(4)));

#define BB    128
#define DIM   384
#define NTOK  256
#define NH    8
#define KD    32
#define DHEAD 128
#define DH    1024
#define SCALE 0.17677669529663687f

// sanitize: NaN->0, clamp huge (free for genuine data; turns dtype/garbage bugs
// into finite absmax fingerprints instead of NaN)
static __device__ __forceinline__ float sf(float x) {
  return (x == x) ? fminf(fmaxf(x, -1e4f), 1e4f) : 0.f;
}

// ---------------- K-1: fp32 weights -> bf16 copies in ws ----------------
// [q_w 98304 | k_w 98304 | v_w 393216 | proj_w 393216] = 983040 elements
__global__ __launch_bounds__(256) void k_convert(const float* __restrict__ qw,
    const float* __restrict__ kw, const float* __restrict__ vw,
    const float* __restrict__ pw, bf16* __restrict__ dst) {
  int i = blockIdx.x * 256 + threadIdx.x;
  float v;
  if (i < 98304)       v = qw[i];
  else if (i < 196608) v = kw[i - 98304];
  else if (i < 589824) v = vw[i - 196608];
  else                 v = pw[i - 589824];
  dst[i] = __float2bfloat16(sf(v));
}

// ---------------- K0: x fp32 [cb,384,256] -> xT bf16 [cb,256,384] ----------------
__global__ __launch_bounds__(256) void k_transpose_x(const float* __restrict__ x,
                                                     bf16* __restrict__ xT) {
  __shared__ bf16 tile[32][33];
  int b = blockIdx.z;
  int c0 = blockIdx.x * 32;
  int n0 = blockIdx.y * 32;
  int t = threadIdx.x;
  int tn = t & 31, tc = t >> 5;
#pragma unroll
  for (int p = 0; p < 4; ++p)
    tile[tc + p * 8][tn] =
        __float2bfloat16(sf(x[((size_t)b * DIM + c0 + tc + p * 8) * NTOK + n0 + tn]));
  __syncthreads();
  int wc = t & 31, wn = t >> 5;
#pragma unroll
  for (int p = 0; p < 4; ++p)
    xT[((size_t)b * NTOK + n0 + wn + p * 8) * DIM + c0 + wc] = tile[wc][wn + p * 8];
}

// ---------------- K1: QKV GEMM (chunk-local batches) ----------------
// weights: bf16 converted copies. biases: fp32 direct.
// writes qT[b,h,n,kd], kT[b,h,m,kd], v4[b,ch,n]
__global__ __launch_bounds__(256) void k_qkv(const bf16* __restrict__ xT,
    const bf16* __restrict__ q_w, const float* __restrict__ q_b,
    const bf16* __restrict__ k_w, const float* __restrict__ k_b,
    const bf16* __restrict__ v_w, const float* __restrict__ v_b,
    bf16* __restrict__ qT, bf16* __restrict__ kT, bf16* __restrict__ v4) {
  int b = blockIdx.y;
  int m0 = blockIdx.x * 64;
  int wave = threadIdx.x >> 6;
  int lane = threadIdx.x & 63;
  int qd = lane >> 4, li = lane & 15;
  int n0 = wave * 64;
  f32x4 acc[4][4];
#pragma unroll
  for (int r = 0; r < 4; ++r)
#pragma unroll
    for (int f = 0; f < 4; ++f) acc[r][f] = (f32x4){0.f, 0.f, 0.f, 0.f};
  for (int k0 = 0; k0 < DIM; k0 += 32) {
    bf16v8 Af[4], Bf[4];
#pragma unroll
    for (int r = 0; r < 4; ++r) {
      int o = m0 + r * 16 + li;
      const bf16* wp = (o < 256) ? (q_w + o * DIM)
                     : (o < 512) ? (k_w + (o - 256) * DIM)
                                 : (v_w + (o - 512) * DIM);
      Af[r] = *(const bf16v8*)(wp + k0 + qd * 8);
    }
#pragma unroll
    for (int f = 0; f < 4; ++f)
      Bf[f] = *(const bf16v8*)(xT + ((size_t)b * NTOK + n0 + f * 16 + li) * DIM + k0 + qd * 8);
#pragma unroll
    for (int r = 0; r < 4; ++r)
#pragma unroll
      for (int f = 0; f < 4; ++f)
        acc[r][f] = __builtin_amdgcn_mfma_f32_16x16x32_bf16(Af[r], Bf[f], acc[r][f], 0, 0, 0);
  }
#pragma unroll
  for (int r = 0; r < 4; ++r) {
#pragma unroll
    for (int f = 0; f < 4; ++f) {
      int n = n0 + f * 16 + li;
#pragma unroll
      for (int rr = 0; rr < 4; ++rr) {
        int o = m0 + r * 16 + qd * 4 + rr;
        float val = acc[r][f][rr];
        if (o < 256) {
          int h = o >> 5, kd = o & 31;
          val += sf(q_b[o]);
          qT[(((size_t)b * NH + h) * NTOK + n) * KD + kd] = __float2bfloat16(val);
        } else if (o < 512) {
          int o2 = o - 256;
          int h = o2 >> 5, kd = o2 & 31;
          val += sf(k_b[o2]);
          kT[(((size_t)b * NH + h) * NTOK + n) * KD + kd] = __float2bfloat16(val);
        } else {
          int ch = o - 512;
          val += sf(v_b[ch]);
          v4[((size_t)b * DH + ch) * NTOK + n] = __float2bfloat16(val);
        }
      }
    }
  }
}

// ---------------- K2: FUSED scores+TH1+softmax+TH2 -> (LDS) -> PV+dwconv+relu -> (LDS) -> proj ----------------
// block = (chunk-local b, one spatial row of 16 queries); 8 waves. LDS ~103 KB.
__global__ __launch_bounds__(512, 2) void k_fused(const bf16* __restrict__ qT,
    const bf16* __restrict__ kT, const bf16* __restrict__ v4,
    const float* __restrict__ ab, const int* __restrict__ idxs, int n_off,
    const float* __restrict__ vl_w, const float* __restrict__ vl_b,
    const float* __restrict__ th1_w, const float* __restrict__ th1_b,
    const float* __restrict__ th2_w, const float* __restrict__ th2_b,
    const bf16* __restrict__ proj_w, const float* __restrict__ proj_b,
    int b_base, float* __restrict__ out) {
  __shared__ bf16 p_lds[NH][16][264];    // 67.6 KB; stride 264: 4-bank skew
  __shared__ bf16 act_lds[16][1032];     // 33 KB
  __shared__ float s_th1[64], s_th2[64], s_t1b[8], s_t2b[8];
  __shared__ float s_part[8][8][16];
  __shared__ float s_invl[8][16];
  int t = threadIdx.x;
  if (t < 64) { s_th1[t] = sf(th1_w[t]); s_th2[t] = sf(th2_w[t]); }
  if (t >= 64 && t < 72) s_t1b[t - 64] = sf(th1_b[t - 64]);
  if (t >= 72 && t < 80) s_t2b[t - 72] = sf(th2_b[t - 72]);
  int b = blockIdx.x >> 4;               // chunk-local batch
  int bg = b_base + b;                   // global batch (for out)
  int nt = blockIdx.x & 15, n0 = nt * 16;
  int wave = t >> 6, lane = t & 63, qd = lane >> 4, li = lane & 15;
  int ms = wave * 32;

  // ---- Phase A1: scores S[h][mt][r] for (n = n0+qd*4+r, m = ms+mt*16+li) ----
  f32x4 S[8][2];
#pragma unroll
  for (int h = 0; h < 8; ++h) {
    bf16v8 Af = *(const bf16v8*)(qT + (((size_t)b * NH + h) * NTOK + n0 + li) * KD + qd * 8);
#pragma unroll
    for (int mt = 0; mt < 2; ++mt) {
      bf16v8 Bf = *(const bf16v8*)(kT + (((size_t)b * NH + h) * NTOK + ms + mt * 16 + li) * KD + qd * 8);
      f32x4 c = {0.f, 0.f, 0.f, 0.f};
      S[h][mt] = __builtin_amdgcn_mfma_f32_16x16x32_bf16(Af, Bf, c, 0, 0, 0);
    }
  }
  int bidx[2][4];
#pragma unroll
  for (int mt = 0; mt < 2; ++mt)
#pragma unroll
    for (int r = 0; r < 4; ++r)
      bidx[mt][r] = idxs[(n0 + qd * 4 + r) * NTOK + ms + mt * 16 + li];
#pragma unroll
  for (int h = 0; h < 8; ++h)
#pragma unroll
    for (int mt = 0; mt < 2; ++mt)
#pragma unroll
      for (int r = 0; r < 4; ++r)
        S[h][mt][r] = S[h][mt][r] * SCALE + sf(ab[h * n_off + bidx[mt][r]]);
  __syncthreads();   // th weights staged

  // ---- Phase A2: TH1 + exp (no max-sub; clamp = overflow firewall) + row sums ----
  float psum[8][4];
#pragma unroll
  for (int g = 0; g < 8; ++g)
#pragma unroll
    for (int r = 0; r < 4; ++r) psum[g][r] = 0.f;
#pragma unroll
  for (int mt = 0; mt < 2; ++mt)
#pragma unroll
    for (int r = 0; r < 4; ++r) {
      float e[8];
#pragma unroll
      for (int g = 0; g < 8; ++g) {
        float a = s_t1b[g];
#pragma unroll
        for (int h = 0; h < 8; ++h) a += s_th1[g * 8 + h] * S[h][mt][r];
        e[g] = __expf(fminf(a, 30.0f));
        psum[g][r] += e[g];
      }
#pragma unroll
      for (int g = 0; g < 8; ++g) S[g][mt][r] = e[g];
    }
#pragma unroll
  for (int g = 0; g < 8; ++g)
#pragma unroll
    for (int r = 0; r < 4; ++r) {
      float v = psum[g][r];
      v += __shfl_xor(v, 1, 64);
      v += __shfl_xor(v, 2, 64);
      v += __shfl_xor(v, 4, 64);
      v += __shfl_xor(v, 8, 64);
      psum[g][r] = v;
    }
  if (li == 0) {
#pragma unroll
    for (int g = 0; g < 8; ++g)
#pragma unroll
      for (int r = 0; r < 4; ++r) s_part[wave][g][qd * 4 + r] = psum[g][r];
  }
  __syncthreads();
  if (t < 128) {
    int g = t >> 4, n = t & 15;
    float ssum = 0.f;
#pragma unroll
    for (int w2 = 0; w2 < 8; ++w2) ssum += s_part[w2][g][n];
    s_invl[g][n] = 1.0f / ssum;
  }
  __syncthreads();
#pragma unroll
  for (int g = 0; g < 8; ++g)
#pragma unroll
    for (int mt = 0; mt < 2; ++mt)
#pragma unroll
      for (int r = 0; r < 4; ++r)
        S[g][mt][r] *= s_invl[g][qd * 4 + r];

  // ---- Phase A3: TH2 + stage P into LDS ----
#pragma unroll
  for (int mt = 0; mt < 2; ++mt)
#pragma unroll
    for (int r = 0; r < 4; ++r) {
      int nl = qd * 4 + r, m = ms + mt * 16 + li;
#pragma unroll
      for (int g2 = 0; g2 < 8; ++g2) {
        float a = s_t2b[g2];
#pragma unroll
        for (int g = 0; g < 8; ++g) a += s_th2[g2 * 8 + g] * S[g][mt][r];
        p_lds[g2][nl][m] = __float2bfloat16(a);
      }
    }
  __syncthreads();

  // ---- Phase B: PV. wave g: O[16n x 128d] for head g; inline dwconv epilogue ----
  int g = wave;
  f32x4 oacc[8];
#pragma unroll
  for (int f = 0; f < 8; ++f) oacc[f] = (f32x4){0.f, 0.f, 0.f, 0.f};
#pragma unroll
  for (int m0 = 0; m0 < NTOK; m0 += 32) {
    bf16v8 Af = *(const bf16v8*)(&p_lds[g][li][m0 + qd * 8]);
#pragma unroll
    for (int f = 0; f < 8; ++f) {
      bf16v8 Bf = *(const bf16v8*)(v4 + ((size_t)b * DH + g * DHEAD + f * 16 + li) * NTOK + m0 + qd * 8);
      oacc[f] = __builtin_amdgcn_mfma_f32_16x16x32_bf16(Af, Bf, oacc[f], 0, 0, 0);
    }
  }
#pragma unroll
  for (int f = 0; f < 8; ++f) {
    int ch = g * DHEAD + f * 16 + li;
    const bf16* vr = v4 + ((size_t)b * DH + ch) * NTOK;
    float wv[9];
#pragma unroll
    for (int j = 0; j < 9; ++j) wv[j] = sf(vl_w[ch * 9 + j]);
    float vb = sf(vl_b[ch]);
#pragma unroll
    for (int rr = 0; rr < 4; ++rr) {
      int nl = qd * 4 + rr;
      float s = vb;
#pragma unroll
      for (int dy = -1; dy <= 1; ++dy) {
        int yy = nt + dy;
        if (yy < 0 || yy > 15) continue;
#pragma unroll
        for (int dx = -1; dx <= 1; ++dx) {
          int xx = nl + dx;
          if (xx < 0 || xx > 15) continue;
          s += __bfloat162float(vr[yy * 16 + xx]) * wv[(dy + 1) * 3 + (dx + 1)];
        }
      }
      float v = fmaxf(oacc[f][rr] + s, 0.f);   // fmaxf swallows NaN garbage
      act_lds[nl][ch] = __float2bfloat16(v);
    }
  }
  __syncthreads();

  // ---- Phase C: proj. wave w: dims [48w, 48w+48) x 16 tokens, K=1024 ----
  int dim0 = wave * 48;
  f32x4 pacc[3];
#pragma unroll
  for (int rt = 0; rt < 3; ++rt) pacc[rt] = (f32x4){0.f, 0.f, 0.f, 0.f};
  for (int k0 = 0; k0 < DH; k0 += 32) {
    bf16v8 Bf = *(const bf16v8*)(&act_lds[li][k0 + qd * 8]);
#pragma unroll
    for (int rt = 0; rt < 3; ++rt) {
      bf16v8 Af = *(const bf16v8*)(proj_w + (size_t)(dim0 + rt * 16 + li) * DH + k0 + qd * 8);
      pacc[rt] = __builtin_amdgcn_mfma_f32_16x16x32_bf16(Af, Bf, pacc[rt], 0, 0, 0);
    }
  }
#pragma unroll
  for (int rt = 0; rt < 3; ++rt)
#pragma unroll
    for (int rr = 0; rr < 4; ++rr) {
      int dim = dim0 + rt * 16 + qd * 4 + rr;
      out[((size_t)bg * DIM + dim) * NTOK + n0 + li] = pacc[rt][rr] + sf(proj_b[dim]);
    }
}

extern "C" void kernel_launch(void* const* d_in, const int* in_sizes, int n_in,
                              void* d_out, int out_size, void* d_ws, size_t ws_size,
                              hipStream_t stream) {
  // Reference dtypes: everything float32 except bias_idxs (int32). Output float32.
  const float* x      = (const float*)d_in[0];
  const float* q_w    = (const float*)d_in[1];
  const float* q_b    = (const float*)d_in[2];
  const float* k_w    = (const float*)d_in[3];
  const float* k_b    = (const float*)d_in[4];
  const float* v_w    = (const float*)d_in[5];
  const float* v_b    = (const float*)d_in[6];
  const float* vl_w   = (const float*)d_in[7];
  const float* vl_b   = (const float*)d_in[8];
  const float* th1_w  = (const float*)d_in[9];
  const float* th1_b  = (const float*)d_in[10];
  const float* th2_w  = (const float*)d_in[11];
  const float* th2_b  = (const float*)d_in[12];
  const float* proj_w = (const float*)d_in[13];
  const float* proj_b = (const float*)d_in[14];
  const float* attn_b = (const float*)d_in[15];
  const int*   idxs   = (const int*)d_in[16];
  int n_off = in_sizes[15] / NH;
  float* out = (float*)d_out;

  // ws: [bf16 weight copies: wq|wk|wv|wp = 983040 elem] + per-chunk buffers
  const size_t WQ = 98304, WK = 98304, WV = 393216, WP = 393216;
  const size_t WTOT = WQ + WK + WV + WP;                     // 983040
  const size_t PB_XT = (size_t)NTOK * DIM;                   // 98304
  const size_t PB_QK = (size_t)NH * NTOK * KD;               // 65536
  const size_t PB_V  = (size_t)DH * NTOK;                    // 262144
  const size_t perb  = (PB_XT + 2 * PB_QK + PB_V) * 2;       // 983040 B/batch

  char* w = (char*)d_ws;
  bf16* wcvt = (bf16*)w;  w += WTOT * 2;
  bf16* wq = wcvt;
  bf16* wk = wcvt + WQ;
  bf16* wv = wcvt + WQ + WK;
  bf16* wp = wcvt + WQ + WK + WV;

  size_t rem = (ws_size > WTOT * 2) ? (ws_size - WTOT * 2) : 0;
  int CH = (int)(rem / perb);
  if (CH > BB) CH = BB;
  if (CH < 1) CH = 1;

  bf16* xT = (bf16*)w;  w += (size_t)CH * PB_XT * 2;
  bf16* qT = (bf16*)w;  w += (size_t)CH * PB_QK * 2;
  bf16* kT = (bf16*)w;  w += (size_t)CH * PB_QK * 2;
  bf16* v4 = (bf16*)w;  w += (size_t)CH * PB_V * 2;

  k_convert<<<(int)(WTOT / 256), 256, 0, stream>>>(q_w, k_w, v_w, proj_w, wcvt);

  for (int c0 = 0; c0 < BB; c0 += CH) {
    int cb = (BB - c0 < CH) ? (BB - c0) : CH;
    k_transpose_x<<<dim3(12, 8, cb), 256, 0, stream>>>(x + (size_t)c0 * DIM * NTOK, xT);
    k_qkv<<<dim3(24, cb), 256, 0, stream>>>(xT, wq, q_b, wk, k_b, wv, v_b, qT, kT, v4);
    k_fused<<<cb * 16, 512, 0, stream>>>(qT, kT, v4, attn_b, idxs, n_off,
                                         vl_w, vl_b, th1_w, th1_b, th2_w, th2_b,
                                         wp, proj_b, c0, out);
  }
}

// Round 6
// 957.476 us; speedup vs baseline: 1.1375x; 1.1375x over previous
//
#include <hip/hip_runtime.h>
#include <hip/hip_bf16.h>

typedef __hip_bfloat16 bf16;
typedef __bf16 bf16v8 __attribute__((ext_vector_type(8)));
typedef float f32x4 __attribute__((ext_vector_type(4)));

#define BB    128
#define DIM   384
#define NTOK  256
#define NH    8
#define KD    32
#define DHEAD 128
#define DH    1024
#define SCALE 0.17677669529663687f

// sanitize boundary reads: NaN->0, clamp huge
static __device__ __forceinline__ float sf(float x) {
  return (x == x) ? fminf(fmaxf(x, -1e4f), 1e4f) : 0.f;
}

// ---------------- K-1: fp32 weights -> bf16 copies in ws ----------------
__global__ __launch_bounds__(256) void k_convert(const float* __restrict__ qw,
    const float* __restrict__ kw, const float* __restrict__ vw,
    const float* __restrict__ pw, bf16* __restrict__ dst) {
  int i = blockIdx.x * 256 + threadIdx.x;
  float v;
  if (i < 98304)       v = qw[i];
  else if (i < 196608) v = kw[i - 98304];
  else if (i < 589824) v = vw[i - 196608];
  else                 v = pw[i - 589824];
  dst[i] = __float2bfloat16(sf(v));
}

// ---------------- K0: x fp32 [cb,384,256] -> xT bf16 [cb,256,384] ----------------
__global__ __launch_bounds__(256) void k_transpose_x(const float* __restrict__ x,
                                                     bf16* __restrict__ xT) {
  __shared__ bf16 tile[32][33];
  int b = blockIdx.z;
  int c0 = blockIdx.x * 32;
  int n0 = blockIdx.y * 32;
  int t = threadIdx.x;
  int tn = t & 31, tc = t >> 5;
#pragma unroll
  for (int p = 0; p < 4; ++p)
    tile[tc + p * 8][tn] =
        __float2bfloat16(sf(x[((size_t)b * DIM + c0 + tc + p * 8) * NTOK + n0 + tn]));
  __syncthreads();
  int wc = t & 31, wn = t >> 5;
#pragma unroll
  for (int p = 0; p < 4; ++p)
    xT[((size_t)b * NTOK + n0 + wn + p * 8) * DIM + c0 + wc] = tile[wc][wn + p * 8];
}

// ---------------- K0b: v4 [cb,1024ch,256tok] -> vT [cb,256tok,1024ch] ----------------
__global__ __launch_bounds__(256) void k_transpose_v(const bf16* __restrict__ v4,
                                                     bf16* __restrict__ vT) {
  __shared__ bf16 tile[32][33];
  int b = blockIdx.z;
  int c0 = blockIdx.x * 32;   // ch
  int n0 = blockIdx.y * 32;   // tok
  int t = threadIdx.x;
  int tn = t & 31, tc = t >> 5;
#pragma unroll
  for (int p = 0; p < 4; ++p)
    tile[tc + p * 8][tn] = v4[((size_t)b * DH + c0 + tc + p * 8) * NTOK + n0 + tn];
  __syncthreads();
  int wc = t & 31, wn = t >> 5;
#pragma unroll
  for (int p = 0; p < 4; ++p)
    vT[((size_t)b * NTOK + n0 + wn + p * 8) * DH + c0 + wc] = tile[wc][wn + p * 8];
}

// ---------------- K1: QKV GEMM (chunk-local; XCD-swizzled grid cb*24) ----------------
__global__ __launch_bounds__(256) void k_qkv(const bf16* __restrict__ xT,
    const bf16* __restrict__ q_w, const float* __restrict__ q_b,
    const bf16* __restrict__ k_w, const float* __restrict__ k_b,
    const bf16* __restrict__ v_w, const float* __restrict__ v_b,
    bf16* __restrict__ qT, bf16* __restrict__ kT, bf16* __restrict__ v4,
    int nb) {
  int id = blockIdx.x;
  int b, mt;
  if ((nb & 7) == 0) {          // all m-tiles of a batch -> same XCD (round-robin id&7)
    int per = nb >> 3;
    int xcd = id & 7, slot = id >> 3;
    b = xcd * per + (slot % per);
    mt = slot / per;            // [0,24)
  } else { b = id / 24; mt = id % 24; }
  int m0 = mt * 64;
  int wave = threadIdx.x >> 6;
  int lane = threadIdx.x & 63;
  int qd = lane >> 4, li = lane & 15;
  int n0 = wave * 64;
  f32x4 acc[4][4];
#pragma unroll
  for (int r = 0; r < 4; ++r)
#pragma unroll
    for (int f = 0; f < 4; ++f) acc[r][f] = (f32x4){0.f, 0.f, 0.f, 0.f};
  for (int k0 = 0; k0 < DIM; k0 += 32) {
    bf16v8 Af[4], Bf[4];
#pragma unroll
    for (int r = 0; r < 4; ++r) {
      int o = m0 + r * 16 + li;
      const bf16* wp = (o < 256) ? (q_w + o * DIM)
                     : (o < 512) ? (k_w + (o - 256) * DIM)
                                 : (v_w + (o - 512) * DIM);
      Af[r] = *(const bf16v8*)(wp + k0 + qd * 8);
    }
#pragma unroll
    for (int f = 0; f < 4; ++f)
      Bf[f] = *(const bf16v8*)(xT + ((size_t)b * NTOK + n0 + f * 16 + li) * DIM + k0 + qd * 8);
#pragma unroll
    for (int r = 0; r < 4; ++r)
#pragma unroll
      for (int f = 0; f < 4; ++f)
        acc[r][f] = __builtin_amdgcn_mfma_f32_16x16x32_bf16(Af[r], Bf[f], acc[r][f], 0, 0, 0);
  }
#pragma unroll
  for (int r = 0; r < 4; ++r) {
#pragma unroll
    for (int f = 0; f < 4; ++f) {
      int n = n0 + f * 16 + li;
#pragma unroll
      for (int rr = 0; rr < 4; ++rr) {
        int o = m0 + r * 16 + qd * 4 + rr;
        float val = acc[r][f][rr];
        if (o < 256) {
          int h = o >> 5, kd = o & 31;
          val += sf(q_b[o]);
          qT[(((size_t)b * NH + h) * NTOK + n) * KD + kd] = __float2bfloat16(val);
        } else if (o < 512) {
          int o2 = o - 256;
          int h = o2 >> 5, kd = o2 & 31;
          val += sf(k_b[o2]);
          kT[(((size_t)b * NH + h) * NTOK + n) * KD + kd] = __float2bfloat16(val);
        } else {
          int ch = o - 512;
          val += sf(v_b[ch]);
          v4[((size_t)b * DH + ch) * NTOK + n] = __float2bfloat16(val);
        }
      }
    }
  }
}

// ---------------- K2: ATTN scores+TH1+softmax+TH2 -> (LDS) -> PV + dwconv + relu -> act ----------------
// block = (chunk-local b, 16-query spatial row); 8 waves; LDS ~72.8 KB -> 2 blocks/CU.
__global__ __launch_bounds__(512, 2) void k_attn(const bf16* __restrict__ qT,
    const bf16* __restrict__ kT, const bf16* __restrict__ v4,
    const bf16* __restrict__ vT,
    const float* __restrict__ ab, const int* __restrict__ idxs, int n_off,
    const float* __restrict__ vl_w, const float* __restrict__ vl_b,
    const float* __restrict__ th1_w, const float* __restrict__ th1_b,
    const float* __restrict__ th2_w, const float* __restrict__ th2_b,
    bf16* __restrict__ act, int nb) {
  __shared__ bf16 p_lds[NH][16][264];    // 67.6 KB; stride 264: 4-bank skew
  __shared__ float s_th1[64], s_th2[64], s_t1b[8], s_t2b[8];
  __shared__ float s_part[8][8][16];
  __shared__ float s_invl[8][16];
  int t = threadIdx.x;
  if (t < 64) { s_th1[t] = sf(th1_w[t]); s_th2[t] = sf(th2_w[t]); }
  if (t >= 64 && t < 72) s_t1b[t - 64] = sf(th1_b[t - 64]);
  if (t >= 72 && t < 80) s_t2b[t - 72] = sf(th2_b[t - 72]);
  int id = blockIdx.x;
  int b, nt;
  if ((nb & 7) == 0) {          // all 16 query-tiles of a batch -> same XCD
    int per = nb >> 3;
    int xcd = id & 7, slot = id >> 3;
    b = xcd * per + (slot % per);
    nt = slot / per;            // [0,16)
  } else { b = id >> 4; nt = id & 15; }
  int n0 = nt * 16;
  int wave = t >> 6, lane = t & 63, qd = lane >> 4, li = lane & 15;
  int ms = wave * 32;

  // ---- Phase A1: scores S[h][mt][r] for (n = n0+qd*4+r, m = ms+mt*16+li) ----
  f32x4 S[8][2];
#pragma unroll
  for (int h = 0; h < 8; ++h) {
    bf16v8 Af = *(const bf16v8*)(qT + (((size_t)b * NH + h) * NTOK + n0 + li) * KD + qd * 8);
#pragma unroll
    for (int mt = 0; mt < 2; ++mt) {
      bf16v8 Bf = *(const bf16v8*)(kT + (((size_t)b * NH + h) * NTOK + ms + mt * 16 + li) * KD + qd * 8);
      f32x4 c = {0.f, 0.f, 0.f, 0.f};
      S[h][mt] = __builtin_amdgcn_mfma_f32_16x16x32_bf16(Af, Bf, c, 0, 0, 0);
    }
  }
  int bidx[2][4];
#pragma unroll
  for (int mt = 0; mt < 2; ++mt)
#pragma unroll
    for (int r = 0; r < 4; ++r)
      bidx[mt][r] = idxs[(n0 + qd * 4 + r) * NTOK + ms + mt * 16 + li];
#pragma unroll
  for (int h = 0; h < 8; ++h)
#pragma unroll
    for (int mt = 0; mt < 2; ++mt)
#pragma unroll
      for (int r = 0; r < 4; ++r)
        S[h][mt][r] = S[h][mt][r] * SCALE + sf(ab[h * n_off + bidx[mt][r]]);
  __syncthreads();   // th weights staged

  // ---- Phase A2: TH1 + exp (no max-sub; clamp firewall) + row sums ----
  float psum[8][4];
#pragma unroll
  for (int g = 0; g < 8; ++g)
#pragma unroll
    for (int r = 0; r < 4; ++r) psum[g][r] = 0.f;
#pragma unroll
  for (int mt = 0; mt < 2; ++mt)
#pragma unroll
    for (int r = 0; r < 4; ++r) {
      float e[8];
#pragma unroll
      for (int g = 0; g < 8; ++g) {
        float a = s_t1b[g];
#pragma unroll
        for (int h = 0; h < 8; ++h) a += s_th1[g * 8 + h] * S[h][mt][r];
        e[g] = __expf(fminf(a, 30.0f));
        psum[g][r] += e[g];
      }
#pragma unroll
      for (int g = 0; g < 8; ++g) S[g][mt][r] = e[g];
    }
#pragma unroll
  for (int g = 0; g < 8; ++g)
#pragma unroll
    for (int r = 0; r < 4; ++r) {
      float v = psum[g][r];
      v += __shfl_xor(v, 1, 64);
      v += __shfl_xor(v, 2, 64);
      v += __shfl_xor(v, 4, 64);
      v += __shfl_xor(v, 8, 64);
      psum[g][r] = v;
    }
  if (li == 0) {
#pragma unroll
    for (int g = 0; g < 8; ++g)
#pragma unroll
      for (int r = 0; r < 4; ++r) s_part[wave][g][qd * 4 + r] = psum[g][r];
  }
  __syncthreads();
  if (t < 128) {
    int g = t >> 4, n = t & 15;
    float ssum = 0.f;
#pragma unroll
    for (int w2 = 0; w2 < 8; ++w2) ssum += s_part[w2][g][n];
    s_invl[g][n] = 1.0f / ssum;
  }
  __syncthreads();
#pragma unroll
  for (int g = 0; g < 8; ++g)
#pragma unroll
    for (int mt = 0; mt < 2; ++mt)
#pragma unroll
      for (int r = 0; r < 4; ++r)
        S[g][mt][r] *= s_invl[g][qd * 4 + r];

  // ---- Phase A3: TH2 + stage P into LDS ----
#pragma unroll
  for (int mt = 0; mt < 2; ++mt)
#pragma unroll
    for (int r = 0; r < 4; ++r) {
      int nl = qd * 4 + r, m = ms + mt * 16 + li;
#pragma unroll
      for (int g2 = 0; g2 < 8; ++g2) {
        float a = s_t2b[g2];
#pragma unroll
        for (int g = 0; g < 8; ++g) a += s_th2[g2 * 8 + g] * S[g][mt][r];
        p_lds[g2][nl][m] = __float2bfloat16(a);
      }
    }
  __syncthreads();

  // ---- Phase B: PV (wave g = head g) + inline dwconv (coalesced via vT) + relu ----
  int g = wave;
  f32x4 oacc[8];
#pragma unroll
  for (int f = 0; f < 8; ++f) oacc[f] = (f32x4){0.f, 0.f, 0.f, 0.f};
#pragma unroll
  for (int m0 = 0; m0 < NTOK; m0 += 32) {
    bf16v8 Af = *(const bf16v8*)(&p_lds[g][li][m0 + qd * 8]);
#pragma unroll
    for (int f = 0; f < 8; ++f) {
      bf16v8 Bf = *(const bf16v8*)(v4 + ((size_t)b * DH + g * DHEAD + f * 16 + li) * NTOK + m0 + qd * 8);
      oacc[f] = __builtin_amdgcn_mfma_f32_16x16x32_bf16(Af, Bf, oacc[f], 0, 0, 0);
    }
  }
  const bf16* vtb = vT + (size_t)b * NTOK * DH;
#pragma unroll
  for (int f = 0; f < 8; ++f) {
    int ch = g * DHEAD + f * 16 + li;
    float wv[9];
#pragma unroll
    for (int j = 0; j < 9; ++j) wv[j] = sf(vl_w[ch * 9 + j]);
    float vb = sf(vl_b[ch]);
    // hoisted 3x6 neighborhood (rows nt-1..nt+1, cols qd*4-1..qd*4+4)
    float vv[3][6];
#pragma unroll
    for (int yy2 = 0; yy2 < 3; ++yy2) {
      int y = nt - 1 + yy2;
#pragma unroll
      for (int c = 0; c < 6; ++c) {
        int x = qd * 4 - 1 + c;
        vv[yy2][c] = (y >= 0 && y < 16 && x >= 0 && x < 16)
                     ? __bfloat162float(vtb[(y * 16 + x) * DH + ch]) : 0.f;
      }
    }
#pragma unroll
    for (int rr = 0; rr < 4; ++rr) {
      float s = vb;
#pragma unroll
      for (int yy2 = 0; yy2 < 3; ++yy2)
#pragma unroll
        for (int j = 0; j < 3; ++j)
          s += vv[yy2][rr + j] * wv[yy2 * 3 + j];
      int nl = qd * 4 + rr;
      float v = fmaxf(oacc[f][rr] + s, 0.f);
      act[((size_t)b * NTOK + n0 + nl) * DH + ch] = __float2bfloat16(v);
    }
  }
}

// ---------------- K3: proj GEMM out[b,dim,tok] = wp @ act^T + proj_b (XCD-swizzled) ----------------
__global__ __launch_bounds__(256, 4) void k_proj(const bf16* __restrict__ act,
    const bf16* __restrict__ proj_w, const float* __restrict__ proj_b,
    int b_base, int nb, float* __restrict__ out) {
  int id = blockIdx.x;
  int b, mt;
  if ((nb & 7) == 0) {          // all 6 dim-tiles of a batch -> same XCD
    int per = nb >> 3;
    int xcd = id & 7, slot = id >> 3;
    b = xcd * per + (slot % per);
    mt = slot / per;            // [0,6)
  } else { b = id / 6; mt = id % 6; }
  int m0 = mt * 64;
  int bg = b_base + b;
  int wave = threadIdx.x >> 6, lane = threadIdx.x & 63;
  int qd = lane >> 4, li = lane & 15;
  int n0 = wave * 64;
  f32x4 acc[4][4];
#pragma unroll
  for (int r = 0; r < 4; ++r)
#pragma unroll
    for (int f = 0; f < 4; ++f) acc[r][f] = (f32x4){0.f, 0.f, 0.f, 0.f};
  for (int k0 = 0; k0 < DH; k0 += 32) {
    bf16v8 Af[4], Bf[4];
#pragma unroll
    for (int r = 0; r < 4; ++r)
      Af[r] = *(const bf16v8*)(proj_w + (size_t)(m0 + r * 16 + li) * DH + k0 + qd * 8);
#pragma unroll
    for (int f = 0; f < 4; ++f)
      Bf[f] = *(const bf16v8*)(act + ((size_t)b * NTOK + n0 + f * 16 + li) * DH + k0 + qd * 8);
#pragma unroll
    for (int r = 0; r < 4; ++r)
#pragma unroll
      for (int f = 0; f < 4; ++f)
        acc[r][f] = __builtin_amdgcn_mfma_f32_16x16x32_bf16(Af[r], Bf[f], acc[r][f], 0, 0, 0);
  }
#pragma unroll
  for (int r = 0; r < 4; ++r)
#pragma unroll
    for (int f = 0; f < 4; ++f) {
      int n = n0 + f * 16 + li;
#pragma unroll
      for (int rr = 0; rr < 4; ++rr) {
        int dim = m0 + r * 16 + qd * 4 + rr;
        out[((size_t)bg * DIM + dim) * NTOK + n] = acc[r][f][rr] + sf(proj_b[dim]);
      }
    }
}

extern "C" void kernel_launch(void* const* d_in, const int* in_sizes, int n_in,
                              void* d_out, int out_size, void* d_ws, size_t ws_size,
                              hipStream_t stream) {
  const float* x      = (const float*)d_in[0];
  const float* q_w    = (const float*)d_in[1];
  const float* q_b    = (const float*)d_in[2];
  const float* k_w    = (const float*)d_in[3];
  const float* k_b    = (const float*)d_in[4];
  const float* v_w    = (const float*)d_in[5];
  const float* v_b    = (const float*)d_in[6];
  const float* vl_w   = (const float*)d_in[7];
  const float* vl_b   = (const float*)d_in[8];
  const float* th1_w  = (const float*)d_in[9];
  const float* th1_b  = (const float*)d_in[10];
  const float* th2_w  = (const float*)d_in[11];
  const float* th2_b  = (const float*)d_in[12];
  const float* proj_w = (const float*)d_in[13];
  const float* proj_b = (const float*)d_in[14];
  const float* attn_b = (const float*)d_in[15];
  const int*   idxs   = (const int*)d_in[16];
  int n_off = in_sizes[15] / NH;
  float* out = (float*)d_out;

  const size_t WQ = 98304, WK = 98304, WV = 393216, WP = 393216;
  const size_t WTOT = WQ + WK + WV + WP;                     // 983040 elem
  const size_t PB_XT = (size_t)NTOK * DIM;                   // 98304
  const size_t PB_QK = (size_t)NH * NTOK * KD;               // 65536
  const size_t PB_V  = (size_t)DH * NTOK;                    // 262144
  const size_t PB_AC = (size_t)NTOK * DH;                    // 262144
  const size_t perb  = (PB_XT + 2 * PB_QK + 2 * PB_V + PB_AC) * 2;  // 2031616 B/batch

  char* w = (char*)d_ws;
  bf16* wcvt = (bf16*)w;  w += WTOT * 2;
  bf16* wq = wcvt;
  bf16* wk = wcvt + WQ;
  bf16* wv = wcvt + WQ + WK;
  bf16* wp = wcvt + WQ + WK + WV;

  size_t rem = (ws_size > WTOT * 2) ? (ws_size - WTOT * 2) : 0;
  int CH = (int)(rem / perb);
  if (CH > BB) CH = BB;
  if (CH >= 8) CH &= ~7;      // multiple of 8 -> XCD swizzle active
  if (CH < 1) CH = 1;

  bf16* xT  = (bf16*)w;  w += (size_t)CH * PB_XT * 2;
  bf16* qT  = (bf16*)w;  w += (size_t)CH * PB_QK * 2;
  bf16* kT  = (bf16*)w;  w += (size_t)CH * PB_QK * 2;
  bf16* v4  = (bf16*)w;  w += (size_t)CH * PB_V * 2;
  bf16* vT  = (bf16*)w;  w += (size_t)CH * PB_V * 2;
  bf16* act = (bf16*)w;  w += (size_t)CH * PB_AC * 2;

  k_convert<<<(int)(WTOT / 256), 256, 0, stream>>>(q_w, k_w, v_w, proj_w, wcvt);

  for (int c0 = 0; c0 < BB; c0 += CH) {
    int cb = (BB - c0 < CH) ? (BB - c0) : CH;
    k_transpose_x<<<dim3(12, 8, cb), 256, 0, stream>>>(x + (size_t)c0 * DIM * NTOK, xT);
    k_qkv<<<cb * 24, 256, 0, stream>>>(xT, wq, q_b, wk, k_b, wv, v_b, qT, kT, v4, cb);
    k_transpose_v<<<dim3(32, 8, cb), 256, 0, stream>>>(v4, vT);
    k_attn<<<cb * 16, 512, 0, stream>>>(qT, kT, v4, vT, attn_b, idxs, n_off,
                                        vl_w, vl_b, th1_w, th1_b, th2_w, th2_b,
                                        act, cb);
    k_proj<<<cb * 6, 256, 0, stream>>>(act, wp, proj_b, c0, cb, out);
  }
}